// Round 5
// baseline (214.544 us; speedup 1.0000x reference)
//
#include <hip/hip_runtime.h>

// CapsuleLayer dynamic routing on MI355X — round 5.
// x: [128, 2048, 8] f32, W: [2048, 32, 8, 16] f32, out v: [128, 32, 16] f32.
// Round-4 was occupancy/latency-bound (19% occ, VALU 44%, both pipe floors
// ~25us vs 75us measured). Fix: 8-wave blocks, wave-parity splits the chunk
// stream (R=4 kept, LDS 80KB -> 2 blocks/CU = 16 waves/CU), counted-vmcnt
// prefetch kept, parity partials combined via LDS at the end.

constexpr int NC = 2048;   // in_caps
constexpr int OC = 32;     // out_caps
constexpr int OD = 16;     // out_dim

typedef const __attribute__((address_space(1))) void* gas1_t;
typedef __attribute__((address_space(3))) void* las3_t;

__device__ __forceinline__ void gld16(const void* g, void* l) {
    __builtin_amdgcn_global_load_lds((gas1_t)g, (las3_t)l, 16, 0, 0);
}

#define MEMFENCE() asm volatile("" ::: "memory")
#define BAR() do { MEMFENCE(); __builtin_amdgcn_s_barrier(); MEMFENCE(); } while (0)

// grid = 512 blocks: bt(8) x nsup(64), XCD-swizzled (the 8 bt-blocks sharing an
// nsup W-slice [512KB] land on one XCD's L2; 8 slices = 4MB = one L2).
// block = 512 threads = 8 waves. Block: b in [bt*16,+16), n in [nsup*32,+32).
// Wave w: wg = w&3 -> b0 = bt*16 + wg*4 (R=4); par = w>>2 -> computes chunks
// t = 2s+par over 16 steps. Lane: o = lane&31, d-half h = lane>>5.
// W LDS: 4 x 16KB ring (chunk t in buffer t&3); staged with pre-swizzled global
// source (unit o*32 + (c ^ (o&7))), read back with the same XOR.
template<bool FIRST, bool ATOMIC>
__global__ __launch_bounds__(512)
void caps_pass(const float* __restrict__ xg, const float* __restrict__ Wg,
               const float* __restrict__ vin, float* __restrict__ pout)
{
    __shared__ float4 Wl[4][1024];   // 64 KB ring; reused as combine scratch
    __shared__ float4 xl[1024];      // 16 KB: [n(32)][b(16)][k(2)]

    const int tid  = threadIdx.x;
    const int bid  = blockIdx.x;
    const int nsup = (bid & 7) | ((bid >> 6) << 3);   // 0..63
    const int bt   = (bid >> 3) & 7;                  // 0..7
    const int w    = __builtin_amdgcn_readfirstlane(tid >> 6);  // 0..7
    const int wg   = w & 3;
    const int par  = w >> 2;
    const int lane = tid & 63;
    const int o    = lane & 31;
    const int h    = lane >> 5;
    const int sw   = o & 7;
    const int b0   = bt * 16 + wg * 4;
    const int nbase = nsup * 32;

    const float4* Wg4 = (const float4*)Wg;
    const float4* xg4 = (const float4*)xg;

    float4 acc[4][2];
#pragma unroll
    for (int r = 0; r < 4; ++r)
#pragma unroll
        for (int qq = 0; qq < 2; ++qq) acc[r][qq] = make_float4(0.f, 0.f, 0.f, 0.f);

    float4 vr[4][2];
    if (!FIRST) {
        const float4* v4 = (const float4*)vin;
#pragma unroll
        for (int r = 0; r < 4; ++r)
#pragma unroll
            for (int qq = 0; qq < 2; ++qq)
                vr[r][qq] = v4[(size_t)(b0 + r) * 128 + o * 4 + h * 2 + qq];
    }

    // ---- prologue: x (2 gld16/thread) + chunk pair 0 (4 gld16/thread) ----
#pragma unroll
    for (int j = 0; j < 2; ++j) {      // x: 1024 units [n][b][k]
        const int L = tid + 512 * j;
        const int n = L >> 5, bb = (L >> 1) & 15, k = L & 1;
        gld16(&xg4[(size_t)(bt * 16 + bb) * 4096 + (size_t)(nbase + n) * 2 + k], &xl[L]);
    }
#pragma unroll
    for (int j = 0; j < 4; ++j) {      // chunks 0,1: 2048 units, pre-swizzled src
        const int L = tid + 512 * j;
        const int cn = L >> 10, u = L & 1023;
        const int oo = u >> 5, cc = u & 31;
        gld16(&Wg4[(size_t)(nbase + cn) * 1024 + oo * 32 + (cc ^ (oo & 7))], &Wl[cn][u]);
    }

#pragma unroll 1
    for (int s = 0; s < 16; ++s) {
        BAR();   // A: all waves finished compute of pair s-1 (ring slots free)
        if (s < 15) {
            const int c0 = 2 * (s + 1);
#pragma unroll
            for (int j = 0; j < 4; ++j) {
                const int L = tid + 512 * j;
                const int cn = L >> 10, u = L & 1023;
                const int oo = u >> 5, cc = u & 31;
                gld16(&Wg4[(size_t)(nbase + c0 + cn) * 1024 + oo * 32 + (cc ^ (oo & 7))],
                      &Wl[(c0 + cn) & 3][u]);
            }
            asm volatile("s_waitcnt vmcnt(4)" ::: "memory");  // pair s landed
        } else {
            asm volatile("s_waitcnt vmcnt(0)" ::: "memory");
        }
        BAR();   // B: pair-s data visible to all waves

        // ---- compute chunk t = 2s + par ----
        const int t = 2 * s + par;
        float xr[4][8];
#pragma unroll
        for (int r = 0; r < 4; ++r) {
            const float4 xa = xl[t * 32 + (wg * 4 + r) * 2 + 0];
            const float4 xb = xl[t * 32 + (wg * 4 + r) * 2 + 1];
            xr[r][0] = xa.x; xr[r][1] = xa.y; xr[r][2] = xa.z; xr[r][3] = xa.w;
            xr[r][4] = xb.x; xr[r][5] = xb.y; xr[r][6] = xb.z; xr[r][7] = xb.w;
        }
        const float4* wrow = &Wl[t & 3][o * 32];

        if (FIRST) {
#pragma unroll
            for (int i = 0; i < 8; ++i)
#pragma unroll
                for (int qq = 0; qq < 2; ++qq) {
                    const float4 wv = wrow[(i * 4 + h * 2 + qq) ^ sw];
#pragma unroll
                    for (int r = 0; r < 4; ++r) {
                        acc[r][qq].x = fmaf(xr[r][i], wv.x, acc[r][qq].x);
                        acc[r][qq].y = fmaf(xr[r][i], wv.y, acc[r][qq].y);
                        acc[r][qq].z = fmaf(xr[r][i], wv.z, acc[r][qq].z);
                        acc[r][qq].w = fmaf(xr[r][i], wv.w, acc[r][qq].w);
                    }
                }
        } else {
            float4 u[4][2];
#pragma unroll
            for (int r = 0; r < 4; ++r)
#pragma unroll
                for (int qq = 0; qq < 2; ++qq) u[r][qq] = make_float4(0.f, 0.f, 0.f, 0.f);
#pragma unroll
            for (int i = 0; i < 8; ++i)
#pragma unroll
                for (int qq = 0; qq < 2; ++qq) {
                    const float4 wv = wrow[(i * 4 + h * 2 + qq) ^ sw];
#pragma unroll
                    for (int r = 0; r < 4; ++r) {
                        u[r][qq].x = fmaf(xr[r][i], wv.x, u[r][qq].x);
                        u[r][qq].y = fmaf(xr[r][i], wv.y, u[r][qq].y);
                        u[r][qq].z = fmaf(xr[r][i], wv.z, u[r][qq].z);
                        u[r][qq].w = fmaf(xr[r][i], wv.w, u[r][qq].w);
                    }
                }
#pragma unroll
            for (int r = 0; r < 4; ++r) {
                float tp = 0.f;
#pragma unroll
                for (int qq = 0; qq < 2; ++qq) {
                    tp = fmaf(u[r][qq].x, vr[r][qq].x, tp);
                    tp = fmaf(u[r][qq].y, vr[r][qq].y, tp);
                    tp = fmaf(u[r][qq].z, vr[r][qq].z, tp);
                    tp = fmaf(u[r][qq].w, vr[r][qq].w, tp);
                }
                const float tt = tp + __shfl_xor(tp, 32);
                // |t| small enough that exp without max-subtract is fp32-safe
                const float e = __expf(tt);
                float Z = e;
                Z += __shfl_xor(Z, 1);
                Z += __shfl_xor(Z, 2);
                Z += __shfl_xor(Z, 4);
                Z += __shfl_xor(Z, 8);
                Z += __shfl_xor(Z, 16);
                const float c = e / Z;
#pragma unroll
                for (int qq = 0; qq < 2; ++qq) {
                    acc[r][qq].x = fmaf(c, u[r][qq].x, acc[r][qq].x);
                    acc[r][qq].y = fmaf(c, u[r][qq].y, acc[r][qq].y);
                    acc[r][qq].z = fmaf(c, u[r][qq].z, acc[r][qq].z);
                    acc[r][qq].w = fmaf(c, u[r][qq].w, acc[r][qq].w);
                }
            }
        }
    }

    // ---- combine parity partials via LDS (Wl reused as scratch) ----
    BAR();   // all compute done; Wl free
    float4* scratch = (float4*)Wl;
    if (par == 1) {
#pragma unroll
        for (int r = 0; r < 4; ++r)
#pragma unroll
            for (int qq = 0; qq < 2; ++qq)
                scratch[wg * 512 + lane * 8 + ((r * 2 + qq) ^ (lane & 7))] = acc[r][qq];
        asm volatile("s_waitcnt lgkmcnt(0)" ::: "memory");
    }
    BAR();   // parity-1 writes visible
    if (par == 0) {
        const float sc = FIRST ? (1.0f / 32.0f) : 1.0f;
#pragma unroll
        for (int r = 0; r < 4; ++r)
#pragma unroll
            for (int qq = 0; qq < 2; ++qq) {
                const float4 p = scratch[wg * 512 + lane * 8 + ((r * 2 + qq) ^ (lane & 7))];
                acc[r][qq].x = (acc[r][qq].x + p.x) * sc;
                acc[r][qq].y = (acc[r][qq].y + p.y) * sc;
                acc[r][qq].z = (acc[r][qq].z + p.z) * sc;
                acc[r][qq].w = (acc[r][qq].w + p.w) * sc;
            }
        if (ATOMIC) {
#pragma unroll
            for (int r = 0; r < 4; ++r) {
                float* sb = pout + (size_t)(b0 + r) * (OC * OD) + o * OD + h * 8;
#pragma unroll
                for (int qq = 0; qq < 2; ++qq) {
                    atomicAdd(sb + qq * 4 + 0, acc[r][qq].x);
                    atomicAdd(sb + qq * 4 + 1, acc[r][qq].y);
                    atomicAdd(sb + qq * 4 + 2, acc[r][qq].z);
                    atomicAdd(sb + qq * 4 + 3, acc[r][qq].w);
                }
            }
        } else {
            // partial store: P4[((nsup*128 + b)*4 + h*2+qq)*32 + o], coalesced
            float4* P4 = (float4*)pout;
#pragma unroll
            for (int r = 0; r < 4; ++r) {
                const size_t base = ((size_t)(nsup * 128 + b0 + r) * 4 + h * 2) * 32 + o;
#pragma unroll
                for (int qq = 0; qq < 2; ++qq)
                    P4[base + (size_t)qq * 32] = acc[r][qq];
            }
        }
    }
}

// Fused reduce (over 64 nsup partials) + squash. grid 64 x 256.
__global__ void reduce_squash(const float* __restrict__ P, const float* __restrict__ vprev,
                              float* __restrict__ vout)
{
    __shared__ float sqb[256];
    const int tid = threadIdx.x;
    const int blk = blockIdx.x;
    const float4* P4 = (const float4*)P;

    float4 a = make_float4(0.f, 0.f, 0.f, 0.f);
#pragma unroll 8
    for (int ns = 0; ns < 64; ++ns) {
        const float4 p = P4[(size_t)ns * 16384 + blk * 256 + tid];
        a.x += p.x; a.y += p.y; a.z += p.z; a.w += p.w;
    }
    sqb[tid] = a.x * a.x + a.y * a.y + a.z * a.z + a.w * a.w;
    __syncthreads();
    const int base = tid & 0x9F;   // clear hq bits (5,6)
    const float sq = sqb[base] + sqb[base + 32] + sqb[base + 64] + sqb[base + 96];
    const float f = sq / ((1.0f + sq) * sqrtf(sq + 1e-8f));

    const int b  = blk * 2 + (tid >> 7);
    const int hq = (tid >> 5) & 3;
    const int o  = tid & 31;
    const size_t unit = (size_t)(b * 32 + o) * 4 + hq;
    float4 r;
    r.x = a.x * f; r.y = a.y * f; r.z = a.z * f; r.w = a.w * f;
    if (vprev) {
        const float4 p = ((const float4*)vprev)[unit];
        r.x += p.x; r.y += p.y; r.z += p.z; r.w += p.w;
    }
    ((float4*)vout)[unit] = r;
}

// atomic-path squash
__global__ void squash_k(const float* __restrict__ s, const float* __restrict__ vprev,
                         float* __restrict__ vout)
{
    const int row = blockIdx.x * blockDim.x + threadIdx.x;
    if (row >= 128 * 32) return;
    const float4* s4 = (const float4*)s;
    float4 t[4];
    float sq = 0.f;
#pragma unroll
    for (int q = 0; q < 4; ++q) {
        t[q] = s4[row * 4 + q];
        sq += t[q].x * t[q].x + t[q].y * t[q].y + t[q].z * t[q].z + t[q].w * t[q].w;
    }
    const float f = sq / ((1.0f + sq) * sqrtf(sq + 1e-8f));
    float4* o4 = (float4*)vout;
#pragma unroll
    for (int q = 0; q < 4; ++q) {
        float4 r;
        r.x = t[q].x * f; r.y = t[q].y * f; r.z = t[q].z * f; r.w = t[q].w * f;
        if (vprev) {
            const float4 p = ((const float4*)vprev)[row * 4 + q];
            r.x += p.x; r.y += p.y; r.z += p.z; r.w += p.w;
        }
        o4[row * 4 + q] = r;
    }
}

extern "C" void kernel_launch(void* const* d_in, const int* in_sizes, int n_in,
                              void* d_out, int out_size, void* d_ws, size_t ws_size,
                              hipStream_t stream)
{
    const float* x = (const float*)d_in[0];
    const float* W = (const float*)d_in[1];
    float* out = (float*)d_out;

    const size_t P_FLOATS = (size_t)64 * 128 * 4 * 32 * 4;   // 16 MB
    const size_t NEED = (P_FLOATS + 2 * 65536) * sizeof(float);

    if (ws_size >= NEED) {
        float* P  = (float*)d_ws;
        float* v0 = P + P_FLOATS;
        float* vs = v0 + 65536;

        caps_pass<true, false><<<dim3(512), dim3(512), 0, stream>>>(x, W, nullptr, P);
        reduce_squash<<<dim3(64), dim3(256), 0, stream>>>(P, nullptr, v0);

        caps_pass<false, false><<<dim3(512), dim3(512), 0, stream>>>(x, W, v0, P);
        reduce_squash<<<dim3(64), dim3(256), 0, stream>>>(P, v0, vs);   // vs = v0+v1

        caps_pass<false, false><<<dim3(512), dim3(512), 0, stream>>>(x, W, vs, P);
        reduce_squash<<<dim3(64), dim3(256), 0, stream>>>(P, nullptr, out);
    } else {
        // fallback: atomic epilogue
        float* s  = (float*)d_ws;
        float* v0 = s + 65536;
        float* vs = v0 + 65536;
        const size_t sbytes = (size_t)65536 * sizeof(float);

        hipMemsetAsync(s, 0, sbytes, stream);
        caps_pass<true, true><<<dim3(512), dim3(512), 0, stream>>>(x, W, nullptr, s);
        squash_k<<<dim3(16), dim3(256), 0, stream>>>(s, nullptr, v0);

        hipMemsetAsync(s, 0, sbytes, stream);
        caps_pass<false, true><<<dim3(512), dim3(512), 0, stream>>>(x, W, v0, s);
        squash_k<<<dim3(16), dim3(256), 0, stream>>>(s, v0, vs);

        hipMemsetAsync(s, 0, sbytes, stream);
        caps_pass<false, true><<<dim3(512), dim3(512), 0, stream>>>(x, W, vs, s);
        squash_k<<<dim3(16), dim3(256), 0, stream>>>(s, nullptr, out);
    }
}

// Round 6
// 195.459 us; speedup vs baseline: 1.0976x; 1.0976x over previous
//
#include <hip/hip_runtime.h>

// CapsuleLayer dynamic routing on MI355X — round 6.
// x: [128, 2048, 8] f32, W: [2048, 32, 8, 16] f32, out v: [128, 32, 16] f32.
// R4/R5 were latency-bound: grid 512 = 2 blocks/CU cap (8 waves/CU), FIRST ==
// non-FIRST time proves staging/barrier structure dominates. Fix: grid 1024
// (16-chunk blocks), LDS 32KB (W ring-2 only; x via wave-uniform scalar loads)
// -> 4 blocks/CU, 16 waves/CU; stalls hidden by cross-block TLP.

constexpr int NC = 2048;   // in_caps
constexpr int OC = 32;     // out_caps
constexpr int OD = 16;     // out_dim

typedef const __attribute__((address_space(1))) void* gas1_t;
typedef __attribute__((address_space(3))) void* las3_t;

__device__ __forceinline__ void gld16(const void* g, void* l) {
    __builtin_amdgcn_global_load_lds((gas1_t)g, (las3_t)l, 16, 0, 0);
}

#define MEMFENCE() asm volatile("" ::: "memory")
#define BAR() do { MEMFENCE(); __builtin_amdgcn_s_barrier(); MEMFENCE(); } while (0)

// NR = n-chunks per block (1 n per chunk). grid = 8 * (2048/NR) blocks,
// bid = bt*(2048/NR) + nsup  ->  bid%8 == nsup%8: the 8 bt-siblings sharing a
// W-slice land on one XCD's L2. block = 256 threads = 4 waves.
// Wave w: b0 = bt*16 + w*4 (R=4 reuse of every LDS W read).
// Lane: o = lane&31, d-half h = lane>>5 (d = h*8 + 0..7).
// W LDS ring-2 (16KB/chunk): float4 unit o*32 + (c ^ (o&7)); linear LDS dest,
// pre-swizzled global source, read back with the same XOR (bank = col%8).
// x: wave-uniform address -> scalar loads into SGPRs (no LDS, no unpack).
template<int NR, bool FIRST, bool ATOMIC>
__global__ __launch_bounds__(256)
void caps_pass(const float* __restrict__ xg, const float* __restrict__ Wg,
               const float* __restrict__ vin, float* __restrict__ pout)
{
    __shared__ float4 Wl[2][1024];   // 32 KB ring

    constexpr int NSUPC = 2048 / NR;
    const int tid  = threadIdx.x;
    const int bid  = blockIdx.x;
    const int bt   = bid / NSUPC;
    const int nsup = bid % NSUPC;
    const int w    = __builtin_amdgcn_readfirstlane(tid >> 6);  // uniform wave id
    const int lane = tid & 63;
    const int o    = lane & 31;
    const int h    = lane >> 5;
    const int sw   = o & 7;
    const int b0   = bt * 16 + w * 4;
    const int nbase = nsup * NR;

    const float4* Wg4 = (const float4*)Wg;

    float4 acc[4][2];
#pragma unroll
    for (int r = 0; r < 4; ++r)
#pragma unroll
        for (int qq = 0; qq < 2; ++qq) acc[r][qq] = make_float4(0.f, 0.f, 0.f, 0.f);

    float4 vr[4][2];
    if (!FIRST) {
        const float4* v4 = (const float4*)vin;
#pragma unroll
        for (int r = 0; r < 4; ++r)
#pragma unroll
            for (int qq = 0; qq < 2; ++qq)
                vr[r][qq] = v4[(size_t)(b0 + r) * 128 + o * 4 + h * 2 + qq];
    }

    // ---- prologue: stage W chunk 0 (4 gld16/thread, pre-swizzled source) ----
#pragma unroll
    for (int j = 0; j < 4; ++j) {
        const int L = tid + 256 * j;           // lane-linear LDS unit
        const int oo = L >> 5, cc = L & 31;
        gld16(&Wg4[(size_t)nbase * 1024 + oo * 32 + (cc ^ (oo & 7))], &Wl[0][L]);
    }

#pragma unroll 1
    for (int t = 0; t < NR; ++t) {
        BAR();   // all waves done computing chunk t-1 -> ring slot (t+1)&1 free
        if (t + 1 < NR) {
#pragma unroll
            for (int j = 0; j < 4; ++j) {
                const int L = tid + 256 * j;
                const int oo = L >> 5, cc = L & 31;
                gld16(&Wg4[(size_t)(nbase + t + 1) * 1024 + oo * 32 + (cc ^ (oo & 7))],
                      &Wl[(t + 1) & 1][L]);
            }
            asm volatile("s_waitcnt vmcnt(4)" ::: "memory");  // chunk t landed
        } else {
            asm volatile("s_waitcnt vmcnt(0)" ::: "memory");
        }
        BAR();   // chunk t visible to all waves

        // ---- compute chunk t (n = nbase + t) ----
        const int n = nbase + t;
        float xs[4][8];   // wave-uniform -> SGPRs via s_load
#pragma unroll
        for (int r = 0; r < 4; ++r) {
            const float* xp = xg + ((size_t)(b0 + r) * NC + n) * 8;
#pragma unroll
            for (int i = 0; i < 8; ++i) xs[r][i] = xp[i];
        }
        const float4* wrow = &Wl[t & 1][o * 32];

        __builtin_amdgcn_s_setprio(1);
        if (FIRST) {
#pragma unroll
            for (int i = 0; i < 8; ++i)
#pragma unroll
                for (int qq = 0; qq < 2; ++qq) {
                    const float4 wv = wrow[(i * 4 + h * 2 + qq) ^ sw];
#pragma unroll
                    for (int r = 0; r < 4; ++r) {
                        acc[r][qq].x = fmaf(xs[r][i], wv.x, acc[r][qq].x);
                        acc[r][qq].y = fmaf(xs[r][i], wv.y, acc[r][qq].y);
                        acc[r][qq].z = fmaf(xs[r][i], wv.z, acc[r][qq].z);
                        acc[r][qq].w = fmaf(xs[r][i], wv.w, acc[r][qq].w);
                    }
                }
        } else {
            float4 u[4][2];
#pragma unroll
            for (int r = 0; r < 4; ++r)
#pragma unroll
                for (int qq = 0; qq < 2; ++qq) u[r][qq] = make_float4(0.f, 0.f, 0.f, 0.f);
#pragma unroll
            for (int i = 0; i < 8; ++i)
#pragma unroll
                for (int qq = 0; qq < 2; ++qq) {
                    const float4 wv = wrow[(i * 4 + h * 2 + qq) ^ sw];
#pragma unroll
                    for (int r = 0; r < 4; ++r) {
                        u[r][qq].x = fmaf(xs[r][i], wv.x, u[r][qq].x);
                        u[r][qq].y = fmaf(xs[r][i], wv.y, u[r][qq].y);
                        u[r][qq].z = fmaf(xs[r][i], wv.z, u[r][qq].z);
                        u[r][qq].w = fmaf(xs[r][i], wv.w, u[r][qq].w);
                    }
                }
#pragma unroll
            for (int r = 0; r < 4; ++r) {
                float tp = 0.f;
#pragma unroll
                for (int qq = 0; qq < 2; ++qq) {
                    tp = fmaf(u[r][qq].x, vr[r][qq].x, tp);
                    tp = fmaf(u[r][qq].y, vr[r][qq].y, tp);
                    tp = fmaf(u[r][qq].z, vr[r][qq].z, tp);
                    tp = fmaf(u[r][qq].w, vr[r][qq].w, tp);
                }
                const float tt = tp + __shfl_xor(tp, 32);
                // |logit| <~ 40 -> exp without max-subtract is fp32-safe
                const float e = __expf(tt);
                float Z = e;
                Z += __shfl_xor(Z, 1);
                Z += __shfl_xor(Z, 2);
                Z += __shfl_xor(Z, 4);
                Z += __shfl_xor(Z, 8);
                Z += __shfl_xor(Z, 16);
                const float c = e / Z;
#pragma unroll
                for (int qq = 0; qq < 2; ++qq) {
                    acc[r][qq].x = fmaf(c, u[r][qq].x, acc[r][qq].x);
                    acc[r][qq].y = fmaf(c, u[r][qq].y, acc[r][qq].y);
                    acc[r][qq].z = fmaf(c, u[r][qq].z, acc[r][qq].z);
                    acc[r][qq].w = fmaf(c, u[r][qq].w, acc[r][qq].w);
                }
            }
        }
        __builtin_amdgcn_s_setprio(0);
    }

    const float sc = FIRST ? (1.0f / 32.0f) : 1.0f;
    if (ATOMIC) {
#pragma unroll
        for (int r = 0; r < 4; ++r) {
            float* sb = pout + (size_t)(b0 + r) * (OC * OD) + o * OD + h * 8;
#pragma unroll
            for (int qq = 0; qq < 2; ++qq) {
                atomicAdd(sb + qq * 4 + 0, acc[r][qq].x * sc);
                atomicAdd(sb + qq * 4 + 1, acc[r][qq].y * sc);
                atomicAdd(sb + qq * 4 + 2, acc[r][qq].z * sc);
                atomicAdd(sb + qq * 4 + 3, acc[r][qq].w * sc);
            }
        }
    } else {
        // partial store: P4[((nsup*128 + b)*4 + h*2+qq)*32 + o], coalesced
        float4* P4 = (float4*)pout;
#pragma unroll
        for (int r = 0; r < 4; ++r) {
            const size_t base = ((size_t)(nsup * 128 + b0 + r) * 4 + h * 2) * 32 + o;
#pragma unroll
            for (int qq = 0; qq < 2; ++qq) {
                float4 v;
                v.x = acc[r][qq].x * sc; v.y = acc[r][qq].y * sc;
                v.z = acc[r][qq].z * sc; v.w = acc[r][qq].w * sc;
                P4[base + (size_t)qq * 32] = v;
            }
        }
    }
}

// Fused reduce (over NS nsup partials) + squash. grid 64 x 256.
template<int NS>
__global__ void reduce_squash(const float* __restrict__ P, const float* __restrict__ vprev,
                              float* __restrict__ vout)
{
    __shared__ float sqb[256];
    const int tid = threadIdx.x;
    const int blk = blockIdx.x;
    const float4* P4 = (const float4*)P;

    float4 a = make_float4(0.f, 0.f, 0.f, 0.f);
#pragma unroll 8
    for (int ns = 0; ns < NS; ++ns) {
        const float4 p = P4[(size_t)ns * 16384 + blk * 256 + tid];
        a.x += p.x; a.y += p.y; a.z += p.z; a.w += p.w;
    }
    sqb[tid] = a.x * a.x + a.y * a.y + a.z * a.z + a.w * a.w;
    __syncthreads();
    const int base = tid & 0x9F;   // clear hq bits (5,6)
    const float sq = sqb[base] + sqb[base + 32] + sqb[base + 64] + sqb[base + 96];
    const float f = sq / ((1.0f + sq) * sqrtf(sq + 1e-8f));

    const int b  = blk * 2 + (tid >> 7);
    const int hq = (tid >> 5) & 3;
    const int o  = tid & 31;
    const size_t unit = (size_t)(b * 32 + o) * 4 + hq;
    float4 r;
    r.x = a.x * f; r.y = a.y * f; r.z = a.z * f; r.w = a.w * f;
    if (vprev) {
        const float4 p = ((const float4*)vprev)[unit];
        r.x += p.x; r.y += p.y; r.z += p.z; r.w += p.w;
    }
    ((float4*)vout)[unit] = r;
}

// atomic-path squash
__global__ void squash_k(const float* __restrict__ s, const float* __restrict__ vprev,
                         float* __restrict__ vout)
{
    const int row = blockIdx.x * blockDim.x + threadIdx.x;
    if (row >= 128 * 32) return;
    const float4* s4 = (const float4*)s;
    float4 t[4];
    float sq = 0.f;
#pragma unroll
    for (int q = 0; q < 4; ++q) {
        t[q] = s4[row * 4 + q];
        sq += t[q].x * t[q].x + t[q].y * t[q].y + t[q].z * t[q].z + t[q].w * t[q].w;
    }
    const float f = sq / ((1.0f + sq) * sqrtf(sq + 1e-8f));
    float4* o4 = (float4*)vout;
#pragma unroll
    for (int q = 0; q < 4; ++q) {
        float4 r;
        r.x = t[q].x * f; r.y = t[q].y * f; r.z = t[q].z * f; r.w = t[q].w * f;
        if (vprev) {
            const float4 p = ((const float4*)vprev)[row * 4 + q];
            r.x += p.x; r.y += p.y; r.z += p.z; r.w += p.w;
        }
        o4[row * 4 + q] = r;
    }
}

extern "C" void kernel_launch(void* const* d_in, const int* in_sizes, int n_in,
                              void* d_out, int out_size, void* d_ws, size_t ws_size,
                              hipStream_t stream)
{
    const float* x = (const float*)d_in[0];
    const float* W = (const float*)d_in[1];
    float* out = (float*)d_out;

    const size_t P1 = (size_t)128 * 128 * 512;   // 8.39M floats = 33.55 MB
    const size_t P2 = (size_t)64 * 128 * 512;    // 16.8 MB
    const size_t NEED1 = (P1 + 2 * 65536) * sizeof(float);
    const size_t NEED2 = (P2 + 2 * 65536) * sizeof(float);

    if (ws_size >= NEED1) {
        // tier 1: grid 1024 (4 blocks/CU), 16 chunks/block, 128 partials
        float* P  = (float*)d_ws;
        float* v0 = P + P1;
        float* vs = v0 + 65536;

        caps_pass<16, true, false><<<dim3(1024), dim3(256), 0, stream>>>(x, W, nullptr, P);
        reduce_squash<128><<<dim3(64), dim3(256), 0, stream>>>(P, nullptr, v0);

        caps_pass<16, false, false><<<dim3(1024), dim3(256), 0, stream>>>(x, W, v0, P);
        reduce_squash<128><<<dim3(64), dim3(256), 0, stream>>>(P, v0, vs);   // vs = v0+v1

        caps_pass<16, false, false><<<dim3(1024), dim3(256), 0, stream>>>(x, W, vs, P);
        reduce_squash<128><<<dim3(64), dim3(256), 0, stream>>>(P, nullptr, out);
    } else if (ws_size >= NEED2) {
        // tier 2: grid 512, 32 chunks/block, 64 partials
        float* P  = (float*)d_ws;
        float* v0 = P + P2;
        float* vs = v0 + 65536;

        caps_pass<32, true, false><<<dim3(512), dim3(256), 0, stream>>>(x, W, nullptr, P);
        reduce_squash<64><<<dim3(64), dim3(256), 0, stream>>>(P, nullptr, v0);

        caps_pass<32, false, false><<<dim3(512), dim3(256), 0, stream>>>(x, W, v0, P);
        reduce_squash<64><<<dim3(64), dim3(256), 0, stream>>>(P, v0, vs);

        caps_pass<32, false, false><<<dim3(512), dim3(256), 0, stream>>>(x, W, vs, P);
        reduce_squash<64><<<dim3(64), dim3(256), 0, stream>>>(P, nullptr, out);
    } else {
        // tier 3: atomic epilogue fallback
        float* s  = (float*)d_ws;
        float* v0 = s + 65536;
        float* vs = v0 + 65536;
        const size_t sbytes = (size_t)65536 * sizeof(float);

        hipMemsetAsync(s, 0, sbytes, stream);
        caps_pass<16, true, true><<<dim3(1024), dim3(256), 0, stream>>>(x, W, nullptr, s);
        squash_k<<<dim3(16), dim3(256), 0, stream>>>(s, nullptr, v0);

        hipMemsetAsync(s, 0, sbytes, stream);
        caps_pass<16, false, true><<<dim3(1024), dim3(256), 0, stream>>>(x, W, v0, s);
        squash_k<<<dim3(16), dim3(256), 0, stream>>>(s, v0, vs);

        hipMemsetAsync(s, 0, sbytes, stream);
        caps_pass<16, false, true><<<dim3(1024), dim3(256), 0, stream>>>(x, W, vs, s);
        squash_k<<<dim3(16), dim3(256), 0, stream>>>(s, nullptr, out);
    }
}